// Round 1
// baseline (663.928 us; speedup 1.0000x reference)
//
#include <hip/hip_runtime.h>
#include <hip/hip_bf16.h>
#include <stdint.h>

#define DIM   1024
#define HID   2048
#define NE    8
#define TTOK  8192
#define BM    128
#define BN    128
#define BK    32
#define RMAX  (TTOK + NE * BM)   /* 9216 padded rows max */
#define MTMAX 72                 /* >= 8192/128 + 7 worst-case m-tiles */

typedef __attribute__((ext_vector_type(8))) short bf16x8;
typedef __attribute__((ext_vector_type(4))) float f32x4;

// fp32 -> bf16 round-to-nearest-even on raw bits
__device__ inline unsigned short f2bf(float f) {
    union { float f; unsigned u; } v; v.f = f;
    unsigned r = v.u + 0x7fffu + ((v.u >> 16) & 1u);
    return (unsigned short)(r >> 16);
}

// async global->LDS, 16B per lane; lds base must be wave-uniform
__device__ inline void async_copy16(const void* g, void* l) {
    __builtin_amdgcn_global_load_lds(
        (__attribute__((address_space(1))) void*)(void*)g,
        (__attribute__((address_space(3))) void*)l,
        16, 0, 0);
}

// ---------------- centroid norms ----------------
__global__ __launch_bounds__(256) void cnorm_k(const float* __restrict__ cent,
                                               float* __restrict__ cnorm) {
    int e = blockIdx.x, tid = threadIdx.x;
    float4 cv = ((const float4*)(cent + (size_t)e * DIM))[tid];
    float ss = cv.x * cv.x + cv.y * cv.y + cv.z * cv.z + cv.w * cv.w;
#pragma unroll
    for (int off = 32; off; off >>= 1) ss += __shfl_down(ss, off);
    __shared__ float red[4];
    int w = tid >> 6, l = tid & 63;
    if (l == 0) red[w] = ss;
    __syncthreads();
    if (tid == 0) cnorm[e] = red[0] + red[1] + red[2] + red[3];
}

// ---------------- rmsnorm scalar + routing (all fp32) ----------------
__global__ __launch_bounds__(256) void route_k(const float* __restrict__ x,
                                               const float* __restrict__ scale,
                                               const float* __restrict__ cent,
                                               const float* __restrict__ cnorm,
                                               float* __restrict__ rarr,
                                               int* __restrict__ ids,
                                               int* __restrict__ counts) {
    int t = blockIdx.x, tid = threadIdx.x;
    float4 xv = ((const float4*)(x + (size_t)t * DIM))[tid];
    float4 sv = ((const float4*)scale)[tid];
    float4 xs; xs.x = xv.x * sv.x; xs.y = xv.y * sv.y; xs.z = xv.z * sv.z; xs.w = xv.w * sv.w;
    float ss = xv.x * xv.x + xv.y * xv.y + xv.z * xv.z + xv.w * xv.w;
    float dot[NE];
#pragma unroll
    for (int e = 0; e < NE; ++e) {
        float4 cv = ((const float4*)(cent + (size_t)e * DIM))[tid];
        dot[e] = xs.x * cv.x + xs.y * cv.y + xs.z * cv.z + xs.w * cv.w;
    }
#pragma unroll
    for (int off = 32; off; off >>= 1) {
        ss += __shfl_down(ss, off);
#pragma unroll
        for (int e = 0; e < NE; ++e) dot[e] += __shfl_down(dot[e], off);
    }
    __shared__ float red[4][NE + 1];
    int w = tid >> 6, l = tid & 63;
    if (l == 0) {
        red[w][0] = ss;
#pragma unroll
        for (int e = 0; e < NE; ++e) red[w][1 + e] = dot[e];
    }
    __syncthreads();
    if (tid == 0) {
        float S = red[0][0] + red[1][0] + red[2][0] + red[3][0];
        float r = rsqrtf(S * (1.0f / DIM) + 1e-6f);
        float best = 3.4e38f; int be = 0;
#pragma unroll
        for (int e = 0; e < NE; ++e) {
            float D = red[0][1 + e] + red[1][1 + e] + red[2][1 + e] + red[3][1 + e];
            float dist = cnorm[e] - 2.0f * r * D;   // nx term dropped (argmin-invariant)
            if (dist < best) { best = dist; be = e; }
        }
        rarr[t] = r; ids[t] = be;
        atomicAdd(&counts[be], 1);
    }
}

// ---------------- segment plan + tile map (1 block) ----------------
__global__ void plan_k(const int* __restrict__ counts, int* __restrict__ cursors,
                       int* __restrict__ tile_e, int* __restrict__ tile_row,
                       int* __restrict__ num_tiles) {
    if (threadIdx.x == 0) {
        int row = 0, nt = 0;
        for (int e = 0; e < NE; ++e) {
            cursors[e] = row;
            int c = counts[e];
            int tiles = (c + BM - 1) / BM;
            for (int i = 0; i < tiles; ++i) { tile_e[nt] = e; tile_row[nt] = row + i * BM; ++nt; }
            row += tiles * BM;
        }
        *num_tiles = nt;
    }
}

// ---------------- scatter tokens into sorted order, write bf16 xn ----------------
__global__ __launch_bounds__(256) void scatter_k(const float* __restrict__ x,
                                                 const float* __restrict__ scale,
                                                 const float* __restrict__ rarr,
                                                 const int* __restrict__ ids,
                                                 int* __restrict__ cursors,
                                                 int* __restrict__ sorted_tok,
                                                 unsigned short* __restrict__ xnS) {
    int t = blockIdx.x, tid = threadIdx.x;
    __shared__ int spos;
    if (tid == 0) {
        int e = ids[t];
        int p = atomicAdd(&cursors[e], 1);
        sorted_tok[p] = t;
        spos = p;
    }
    __syncthreads();
    int pos = spos;
    float r = rarr[t];
    float4 xv = ((const float4*)(x + (size_t)t * DIM))[tid];
    float4 sv = ((const float4*)scale)[tid];
    ushort4 o;
    o.x = f2bf(xv.x * sv.x * r); o.y = f2bf(xv.y * sv.y * r);
    o.z = f2bf(xv.z * sv.z * r); o.w = f2bf(xv.w * sv.w * r);
    ((ushort4*)(xnS + (size_t)pos * DIM))[tid] = o;
}

// ---------------- weight transpose + fp32->bf16: [E][Kd][Nd] -> [E][Nd][Kd] ----------------
__global__ __launch_bounds__(256) void transpose_w(const float* __restrict__ W,
                                                   unsigned short* __restrict__ Wt,
                                                   int Kd, int Nd) {
    __shared__ float tile[64][65];
    int e = blockIdx.z;
    const float* src = W + (size_t)e * Kd * Nd;
    unsigned short* dst = Wt + (size_t)e * Kd * Nd;
    int n0 = blockIdx.x * 64, k0 = blockIdx.y * 64;
    int tx = threadIdx.x, ty = threadIdx.y;
#pragma unroll
    for (int i = ty; i < 64; i += 4)
        tile[i][tx] = src[(size_t)(k0 + i) * Nd + n0 + tx];
    __syncthreads();
#pragma unroll
    for (int i = ty; i < 64; i += 4)
        dst[(size_t)(n0 + i) * Kd + k0 + tx] = f2bf(tile[tx][i]);
}

// ---------------- up GEMM (dual tile: a & g) + fused swiglu ----------------
__global__ __launch_bounds__(256, 2) void gemm_up(const unsigned short* __restrict__ xnS,
                                                  const unsigned short* __restrict__ upT,
                                                  unsigned short* __restrict__ act,
                                                  const int* __restrict__ tile_e,
                                                  const int* __restrict__ tile_row,
                                                  const int* __restrict__ num_tiles) {
    int mt = blockIdx.x;
    if (mt >= *num_tiles) return;
    int n0 = blockIdx.y * BN;
    int e = tile_e[mt], row0 = tile_row[mt];

    __shared__ __align__(16) unsigned short As[BM * BK];
    __shared__ __align__(16) unsigned short Ba[BM * BK];
    __shared__ __align__(16) unsigned short Bg[BM * BK];

    const int tid = threadIdx.x;
    const int w = tid >> 6, l = tid & 63;
    const int lrow = l & 15, quad = l >> 4;
    const int m_off = (w >> 1) * 64, n_off = (w & 1) * 64;

    // staging: wave w handles LDS slices 2w, 2w+1 (1024B each = 16 rows of 64B)
    const int sl0 = w * 2, sl1 = w * 2 + 1;
    const int r0 = sl0 * 16 + (l >> 2), r1 = sl1 * 16 + (l >> 2);
    const int kof = (l & 3) * 8;

    const unsigned short* gA0 = xnS + (size_t)(row0 + r0) * DIM + kof;
    const unsigned short* gA1 = xnS + (size_t)(row0 + r1) * DIM + kof;
    const unsigned short* upE = upT + (size_t)e * (2 * HID) * DIM;
    const unsigned short* gBa0 = upE + (size_t)(n0 + r0) * DIM + kof;
    const unsigned short* gBa1 = upE + (size_t)(n0 + r1) * DIM + kof;
    const unsigned short* gBg0 = upE + (size_t)(HID + n0 + r0) * DIM + kof;
    const unsigned short* gBg1 = upE + (size_t)(HID + n0 + r1) * DIM + kof;

    void* lA0 = (char*)As + sl0 * 1024; void* lA1 = (char*)As + sl1 * 1024;
    void* lBa0 = (char*)Ba + sl0 * 1024; void* lBa1 = (char*)Ba + sl1 * 1024;
    void* lBg0 = (char*)Bg + sl0 * 1024; void* lBg1 = (char*)Bg + sl1 * 1024;

    f32x4 accA[4][4], accG[4][4];
#pragma unroll
    for (int i = 0; i < 4; ++i)
#pragma unroll
        for (int j = 0; j < 4; ++j) {
            accA[i][j] = (f32x4){0.f, 0.f, 0.f, 0.f};
            accG[i][j] = (f32x4){0.f, 0.f, 0.f, 0.f};
        }

    const int NT = DIM / BK;
    for (int kt = 0; kt < NT; ++kt) {
        if (kt) __syncthreads();
        const int ko = kt * BK;
        async_copy16(gA0 + ko, lA0);
        async_copy16(gA1 + ko, lA1);
        async_copy16(gBa0 + ko, lBa0);
        async_copy16(gBa1 + ko, lBa1);
        async_copy16(gBg0 + ko, lBg0);
        async_copy16(gBg1 + ko, lBg1);
        __syncthreads();

        bf16x8 af[4], ba[4], bg[4];
#pragma unroll
        for (int mi = 0; mi < 4; ++mi)
            af[mi] = *(const bf16x8*)(As + (m_off + mi * 16 + lrow) * BK + quad * 8);
#pragma unroll
        for (int ni = 0; ni < 4; ++ni) {
            ba[ni] = *(const bf16x8*)(Ba + (n_off + ni * 16 + lrow) * BK + quad * 8);
            bg[ni] = *(const bf16x8*)(Bg + (n_off + ni * 16 + lrow) * BK + quad * 8);
        }
#pragma unroll
        for (int mi = 0; mi < 4; ++mi)
#pragma unroll
            for (int ni = 0; ni < 4; ++ni) {
                accA[mi][ni] = __builtin_amdgcn_mfma_f32_16x16x32_bf16(af[mi], ba[ni], accA[mi][ni], 0, 0, 0);
                accG[mi][ni] = __builtin_amdgcn_mfma_f32_16x16x32_bf16(af[mi], bg[ni], accG[mi][ni], 0, 0, 0);
            }
    }

    // epilogue: act = a * silu(g), bf16
#pragma unroll
    for (int mi = 0; mi < 4; ++mi)
#pragma unroll
        for (int ni = 0; ni < 4; ++ni)
#pragma unroll
            for (int r = 0; r < 4; ++r) {
                float a = accA[mi][ni][r];
                float g = accG[mi][ni][r];
                float s = a * (g / (1.0f + __expf(-g)));
                int gr = row0 + m_off + mi * 16 + quad * 4 + r;
                int gc = n0 + n_off + ni * 16 + lrow;
                act[(size_t)gr * HID + gc] = f2bf(s);
            }
}

// ---------------- down GEMM + residual + scatter to d_out ----------------
__global__ __launch_bounds__(256, 2) void gemm_down(const unsigned short* __restrict__ act,
                                                    const unsigned short* __restrict__ downT,
                                                    const int* __restrict__ sorted_tok,
                                                    const float* __restrict__ x,
                                                    float* __restrict__ out,
                                                    const int* __restrict__ tile_e,
                                                    const int* __restrict__ tile_row,
                                                    const int* __restrict__ num_tiles) {
    int mt = blockIdx.x;
    if (mt >= *num_tiles) return;
    int n0 = blockIdx.y * BN;
    int e = tile_e[mt], row0 = tile_row[mt];

    __shared__ __align__(16) unsigned short As[BM * BK];
    __shared__ __align__(16) unsigned short Bs[BM * BK];

    const int tid = threadIdx.x;
    const int w = tid >> 6, l = tid & 63;
    const int lrow = l & 15, quad = l >> 4;
    const int m_off = (w >> 1) * 64, n_off = (w & 1) * 64;

    const int sl0 = w * 2, sl1 = w * 2 + 1;
    const int r0 = sl0 * 16 + (l >> 2), r1 = sl1 * 16 + (l >> 2);
    const int kof = (l & 3) * 8;

    const unsigned short* gA0 = act + (size_t)(row0 + r0) * HID + kof;
    const unsigned short* gA1 = act + (size_t)(row0 + r1) * HID + kof;
    const unsigned short* dnE = downT + (size_t)e * DIM * HID;
    const unsigned short* gB0 = dnE + (size_t)(n0 + r0) * HID + kof;
    const unsigned short* gB1 = dnE + (size_t)(n0 + r1) * HID + kof;

    void* lA0 = (char*)As + sl0 * 1024; void* lA1 = (char*)As + sl1 * 1024;
    void* lB0 = (char*)Bs + sl0 * 1024; void* lB1 = (char*)Bs + sl1 * 1024;

    f32x4 acc[4][4];
#pragma unroll
    for (int i = 0; i < 4; ++i)
#pragma unroll
        for (int j = 0; j < 4; ++j) acc[i][j] = (f32x4){0.f, 0.f, 0.f, 0.f};

    const int NT = HID / BK;
    for (int kt = 0; kt < NT; ++kt) {
        if (kt) __syncthreads();
        const int ko = kt * BK;
        async_copy16(gA0 + ko, lA0);
        async_copy16(gA1 + ko, lA1);
        async_copy16(gB0 + ko, lB0);
        async_copy16(gB1 + ko, lB1);
        __syncthreads();

        bf16x8 af[4], bf[4];
#pragma unroll
        for (int mi = 0; mi < 4; ++mi)
            af[mi] = *(const bf16x8*)(As + (m_off + mi * 16 + lrow) * BK + quad * 8);
#pragma unroll
        for (int ni = 0; ni < 4; ++ni)
            bf[ni] = *(const bf16x8*)(Bs + (n_off + ni * 16 + lrow) * BK + quad * 8);
#pragma unroll
        for (int mi = 0; mi < 4; ++mi)
#pragma unroll
            for (int ni = 0; ni < 4; ++ni)
                acc[mi][ni] = __builtin_amdgcn_mfma_f32_16x16x32_bf16(af[mi], bf[ni], acc[mi][ni], 0, 0, 0);
    }

    // epilogue: out[tok] = y + x[tok]; skip padding rows (tok = -1)
#pragma unroll
    for (int mi = 0; mi < 4; ++mi)
#pragma unroll
        for (int r = 0; r < 4; ++r) {
            int gr = row0 + m_off + mi * 16 + quad * 4 + r;
            int tok = sorted_tok[gr];
            if (tok >= 0) {
#pragma unroll
                for (int ni = 0; ni < 4; ++ni) {
                    int gc = n0 + n_off + ni * 16 + lrow;
                    size_t idx = (size_t)tok * DIM + gc;
                    out[idx] = acc[mi][ni][r] + x[idx];
                }
            }
        }
}

extern "C" void kernel_launch(void* const* d_in, const int* in_sizes, int n_in,
                              void* d_out, int out_size, void* d_ws, size_t ws_size,
                              hipStream_t stream) {
    const float* x      = (const float*)d_in[0];
    const float* scale  = (const float*)d_in[1];
    const float* cent   = (const float*)d_in[2];
    const float* up_w   = (const float*)d_in[3];
    const float* down_w = (const float*)d_in[4];
    float* out = (float*)d_out;
    char* ws = (char*)d_ws;

    // ---- workspace layout (bytes) ----
    int*   counts     = (int*)(ws + 0);      // 8
    int*   cursors    = (int*)(ws + 32);     // 8
    int*   num_tiles  = (int*)(ws + 96);     // 1
    int*   tile_e     = (int*)(ws + 128);    // MTMAX
    int*   tile_row   = (int*)(ws + 416);    // MTMAX
    float* cnorm      = (float*)(ws + 704);  // 8
    float* rarr       = (float*)(ws + 1024);                 // TTOK
    int*   ids        = (int*)(ws + 1024 + TTOK * 4);        // TTOK
    int*   sorted_tok = (int*)(ws + 1024 + TTOK * 8);        // RMAX
    size_t off = 103424;                                     // 256-aligned
    unsigned short* xnS   = (unsigned short*)(ws + off);     off += (size_t)RMAX * DIM * 2;
    unsigned short* act   = (unsigned short*)(ws + off);     off += (size_t)RMAX * HID * 2;
    unsigned short* upT   = (unsigned short*)(ws + off);     off += (size_t)NE * 2 * HID * DIM * 2;
    unsigned short* downT = (unsigned short*)(ws + off);     off += (size_t)NE * DIM * HID * 2;

    // zero the meta block (counts etc.), mark pad rows, zero xn pad rows
    hipMemsetAsync(ws, 0, 1024, stream);
    hipMemsetAsync(sorted_tok, 0xFF, (size_t)RMAX * 4, stream);
    hipMemsetAsync(xnS, 0, (size_t)RMAX * DIM * 2, stream);

    cnorm_k<<<NE, 256, 0, stream>>>(cent, cnorm);
    route_k<<<TTOK, 256, 0, stream>>>(x, scale, cent, cnorm, rarr, ids, counts);
    plan_k<<<1, 64, 0, stream>>>(counts, cursors, tile_e, tile_row, num_tiles);
    scatter_k<<<TTOK, 256, 0, stream>>>(x, scale, rarr, ids, cursors, sorted_tok, xnS);

    transpose_w<<<dim3(2 * HID / 64, DIM / 64, NE), dim3(64, 4), 0, stream>>>(up_w, upT, DIM, 2 * HID);
    transpose_w<<<dim3(DIM / 64, HID / 64, NE), dim3(64, 4), 0, stream>>>(down_w, downT, HID, DIM);

    gemm_up<<<dim3(MTMAX, HID / BN), 256, 0, stream>>>(xnS, upT, act, tile_e, tile_row, num_tiles);
    gemm_down<<<dim3(MTMAX, DIM / BN), 256, 0, stream>>>(act, downT, sorted_tok, x, out,
                                                         tile_e, tile_row, num_tiles);
}

// Round 3
// 639.233 us; speedup vs baseline: 1.0386x; 1.0386x over previous
//
#include <hip/hip_runtime.h>
#include <hip/hip_bf16.h>
#include <stdint.h>

#define DIM   1024
#define HID   2048
#define NE    8
#define TTOK  8192
#define BM    128
#define BN    128
#define BK    32
#define RMAX  (TTOK + NE * BM)   /* 9216 padded rows max */
#define MTMAX 72                 /* >= 8192/128 + 7 worst-case m-tiles */

typedef __attribute__((ext_vector_type(8))) short bf16x8;
typedef __attribute__((ext_vector_type(8))) unsigned short u16x8;
typedef __attribute__((ext_vector_type(4))) float f32x4;

// fp32 -> bf16 round-to-nearest-even on raw bits
__device__ inline unsigned short f2bf(float f) {
    union { float f; unsigned u; } v; v.f = f;
    unsigned r = v.u + 0x7fffu + ((v.u >> 16) & 1u);
    return (unsigned short)(r >> 16);
}

// async global->LDS, 16B per lane; lds base must be wave-uniform,
// global address may be fully per-lane (gather).
__device__ inline void async_copy16(const void* g, void* l) {
    __builtin_amdgcn_global_load_lds(
        (__attribute__((address_space(1))) void*)(void*)g,
        (__attribute__((address_space(3))) void*)l,
        16, 0, 0);
}

// ---------------- centroid norms ----------------
__global__ __launch_bounds__(256) void cnorm_k(const float* __restrict__ cent,
                                               float* __restrict__ cnorm) {
    int e = blockIdx.x, tid = threadIdx.x;
    float4 cv = ((const float4*)(cent + (size_t)e * DIM))[tid];
    float ss = cv.x * cv.x + cv.y * cv.y + cv.z * cv.z + cv.w * cv.w;
#pragma unroll
    for (int off = 32; off; off >>= 1) ss += __shfl_down(ss, off);
    __shared__ float red[4];
    int w = tid >> 6, l = tid & 63;
    if (l == 0) red[w] = ss;
    __syncthreads();
    if (tid == 0) cnorm[e] = red[0] + red[1] + red[2] + red[3];
}

// ------- rmsnorm + routing (fp32 exact) + write bf16 xn in TOKEN order -------
__global__ __launch_bounds__(256) void route_k(const float* __restrict__ x,
                                               const float* __restrict__ scale,
                                               const float* __restrict__ cent,
                                               const float* __restrict__ cnorm,
                                               int* __restrict__ ids,
                                               int* __restrict__ counts,
                                               unsigned short* __restrict__ xn) {
    int t = blockIdx.x, tid = threadIdx.x;
    float4 xv = ((const float4*)(x + (size_t)t * DIM))[tid];
    float4 sv = ((const float4*)scale)[tid];
    float4 xs; xs.x = xv.x * sv.x; xs.y = xv.y * sv.y; xs.z = xv.z * sv.z; xs.w = xv.w * sv.w;
    float ss = xv.x * xv.x + xv.y * xv.y + xv.z * xv.z + xv.w * xv.w;
    float dot[NE];
#pragma unroll
    for (int e = 0; e < NE; ++e) {
        float4 cv = ((const float4*)(cent + (size_t)e * DIM))[tid];
        dot[e] = xs.x * cv.x + xs.y * cv.y + xs.z * cv.z + xs.w * cv.w;
    }
#pragma unroll
    for (int off = 32; off; off >>= 1) {
        ss += __shfl_down(ss, off);
#pragma unroll
        for (int e = 0; e < NE; ++e) dot[e] += __shfl_down(dot[e], off);
    }
    __shared__ float red[4][NE + 1];
    __shared__ float r_sh;
    int w = tid >> 6, l = tid & 63;
    if (l == 0) {
        red[w][0] = ss;
#pragma unroll
        for (int e = 0; e < NE; ++e) red[w][1 + e] = dot[e];
    }
    __syncthreads();
    if (tid == 0) {
        float S = red[0][0] + red[1][0] + red[2][0] + red[3][0];
        float r = rsqrtf(S * (1.0f / DIM) + 1e-6f);
        float best = 3.4e38f; int be = 0;
#pragma unroll
        for (int e = 0; e < NE; ++e) {
            float D = red[0][1 + e] + red[1][1 + e] + red[2][1 + e] + red[3][1 + e];
            float dist = cnorm[e] - 2.0f * r * D;   // nx term dropped (argmin-invariant)
            if (dist < best) { best = dist; be = e; }
        }
        ids[t] = be;
        atomicAdd(&counts[be], 1);
        r_sh = r;
    }
    __syncthreads();
    float r = r_sh;
    ushort4 o;
    o.x = f2bf(xs.x * r); o.y = f2bf(xs.y * r);
    o.z = f2bf(xs.z * r); o.w = f2bf(xs.w * r);
    ((ushort4*)(xn + (size_t)t * DIM))[tid] = o;
}

// ---------------- segment plan + tile map (1 block) ----------------
__global__ void plan_k(const int* __restrict__ counts, int* __restrict__ cursors,
                       int* __restrict__ tile_e, int* __restrict__ tile_row,
                       int* __restrict__ num_tiles) {
    if (threadIdx.x == 0) {
        int row = 0, nt = 0;
        for (int e = 0; e < NE; ++e) {
            cursors[e] = row;
            int c = counts[e];
            int tiles = (c + BM - 1) / BM;
            for (int i = 0; i < tiles; ++i) { tile_e[nt] = e; tile_row[nt] = row + i * BM; ++nt; }
            row += tiles * BM;
        }
        *num_tiles = nt;
    }
}

// ------- assign sorted slots (ballot-aggregated atomics: 1 per wave per expert) -------
__global__ __launch_bounds__(256) void place_k(const int* __restrict__ ids,
                                               int* __restrict__ cursors,
                                               int* __restrict__ sorted_tok) {
    int t = blockIdx.x * 256 + threadIdx.x;
    int e = ids[t];
    int lane = threadIdx.x & 63;
    int pos = 0;
#pragma unroll
    for (int ee = 0; ee < NE; ++ee) {
        unsigned long long grp = __ballot(e == ee);
        if (e == ee) {
            int leader = __ffsll((unsigned long long)grp) - 1;
            int base = 0;
            if (lane == leader) base = atomicAdd(&cursors[ee], (int)__popcll(grp));
            base = __shfl(base, leader);
            pos = base + (int)__popcll(grp & ((1ull << lane) - 1ull));
        }
    }
    sorted_tok[pos] = t;
}

// ------- weight transpose + fp32->bf16: [E][Kd][Nd] -> [E][Nd][Kd], 16B stores -------
__global__ __launch_bounds__(256) void transpose_w(const float* __restrict__ W,
                                                   unsigned short* __restrict__ Wt,
                                                   int Kd, int Nd) {
    __shared__ unsigned short tile[64][68];   // [n][k], +4 pad
    int e = blockIdx.z;
    const float* src = W + (size_t)e * Kd * Nd;
    unsigned short* dst = Wt + (size_t)e * Kd * Nd;
    int n0 = blockIdx.x * 64, k0 = blockIdx.y * 64;
    int tx = threadIdx.x & 63;
    int ty = threadIdx.x >> 6;
#pragma unroll
    for (int i = ty; i < 64; i += 4)          // i = k row; 256B coalesced reads
        tile[tx][i] = f2bf(src[(size_t)(k0 + i) * Nd + n0 + tx]);
    __syncthreads();
    int i = threadIdx.x >> 2;                 // n row
    int j = threadIdx.x & 3;                  // 16-element k chunk
    u16x8 p0, p1;
#pragma unroll
    for (int kk = 0; kk < 8; ++kk) {
        p0[kk] = tile[i][j * 16 + kk];
        p1[kk] = tile[i][j * 16 + 8 + kk];
    }
    unsigned short* drow = dst + (size_t)(n0 + i) * Kd + k0 + j * 16;
    *(u16x8*)drow = p0;                       // 16B-aligned stores
    *(u16x8*)(drow + 8) = p1;
}

// ---------------- up GEMM (dual tile: a & g) + fused swiglu ----------------
// LDS is FRAGMENT-LINEAR: slot(row,q) = (row>>4)*64 + q*16 + (row&15)  [16B slots]
// => fragment read is lane l -> byte 16*l (conflict-free); the gather pattern of
// global_load_lds realizes this layout (and A rows indirect through sorted_tok).
__global__ __launch_bounds__(256, 2) void gemm_up(const unsigned short* __restrict__ xn,
                                                  const unsigned short* __restrict__ upT,
                                                  unsigned short* __restrict__ act,
                                                  const int* __restrict__ sorted_tok,
                                                  const int* __restrict__ tile_e,
                                                  const int* __restrict__ tile_row,
                                                  const int* __restrict__ num_tiles) {
    int mt = blockIdx.x;
    if (mt >= *num_tiles) return;
    int n0 = blockIdx.y * BN;
    int e = tile_e[mt], row0 = tile_row[mt];

    __shared__ __align__(16) unsigned short As[BM * BK];
    __shared__ __align__(16) unsigned short Ba[BM * BK];
    __shared__ __align__(16) unsigned short Bg[BM * BK];

    const int tid = threadIdx.x;
    const int w = tid >> 6, l = tid & 63;
    const int rl = l & 15, q = l >> 4;
    const int m_off = (w >> 1) * 64, n_off = (w & 1) * 64;
    const int g0 = 2 * w, g1 = 2 * w + 1;

    // A rows gather through sorted_tok; pad rows (-1) clamp to 0 (dead data)
    int tok0 = sorted_tok[row0 + 16 * g0 + rl]; if (tok0 < 0) tok0 = 0;
    int tok1 = sorted_tok[row0 + 16 * g1 + rl]; if (tok1 < 0) tok1 = 0;
    const unsigned short* gA0 = xn + (size_t)tok0 * DIM + q * 8;
    const unsigned short* gA1 = xn + (size_t)tok1 * DIM + q * 8;
    const unsigned short* upE = upT + (size_t)e * (2 * HID) * DIM;
    const unsigned short* gBa0 = upE + (size_t)(n0 + 16 * g0 + rl) * DIM + q * 8;
    const unsigned short* gBa1 = upE + (size_t)(n0 + 16 * g1 + rl) * DIM + q * 8;
    const unsigned short* gBg0 = upE + (size_t)(HID + n0 + 16 * g0 + rl) * DIM + q * 8;
    const unsigned short* gBg1 = upE + (size_t)(HID + n0 + 16 * g1 + rl) * DIM + q * 8;

    unsigned short* lA0 = As + g0 * 512;  unsigned short* lA1 = As + g1 * 512;
    unsigned short* lBa0 = Ba + g0 * 512; unsigned short* lBa1 = Ba + g1 * 512;
    unsigned short* lBg0 = Bg + g0 * 512; unsigned short* lBg1 = Bg + g1 * 512;

    f32x4 accA[4][4], accG[4][4];
#pragma unroll
    for (int i = 0; i < 4; ++i)
#pragma unroll
        for (int j = 0; j < 4; ++j) {
            accA[i][j] = (f32x4){0.f, 0.f, 0.f, 0.f};
            accG[i][j] = (f32x4){0.f, 0.f, 0.f, 0.f};
        }

    const int mg = (w >> 1) * 4;   // m row-group base for this wave
    const int ng = (w & 1) * 4;    // n row-group base

    const int NT = DIM / BK;
    for (int kt = 0; kt < NT; ++kt) {
        if (kt) __syncthreads();
        const int ko = kt * BK;
        async_copy16(gA0 + ko, lA0);
        async_copy16(gA1 + ko, lA1);
        async_copy16(gBa0 + ko, lBa0);
        async_copy16(gBa1 + ko, lBa1);
        async_copy16(gBg0 + ko, lBg0);
        async_copy16(gBg1 + ko, lBg1);
        __syncthreads();

        bf16x8 af[4], ba[4], bg[4];
#pragma unroll
        for (int mi = 0; mi < 4; ++mi)
            af[mi] = *(const bf16x8*)(As + (mg + mi) * 512 + l * 8);
#pragma unroll
        for (int ni = 0; ni < 4; ++ni) {
            ba[ni] = *(const bf16x8*)(Ba + (ng + ni) * 512 + l * 8);
            bg[ni] = *(const bf16x8*)(Bg + (ng + ni) * 512 + l * 8);
        }
#pragma unroll
        for (int mi = 0; mi < 4; ++mi)
#pragma unroll
            for (int ni = 0; ni < 4; ++ni) {
                accA[mi][ni] = __builtin_amdgcn_mfma_f32_16x16x32_bf16(af[mi], ba[ni], accA[mi][ni], 0, 0, 0);
                accG[mi][ni] = __builtin_amdgcn_mfma_f32_16x16x32_bf16(af[mi], bg[ni], accG[mi][ni], 0, 0, 0);
            }
    }

    // epilogue: act = a * silu(g), bf16 (pad rows write garbage -> dead)
#pragma unroll
    for (int mi = 0; mi < 4; ++mi)
#pragma unroll
        for (int ni = 0; ni < 4; ++ni)
#pragma unroll
            for (int r = 0; r < 4; ++r) {
                float a = accA[mi][ni][r];
                float g = accG[mi][ni][r];
                float s = a * (g / (1.0f + __expf(-g)));
                int gr = row0 + m_off + mi * 16 + q * 4 + r;
                int gc = n0 + n_off + ni * 16 + rl;
                act[(size_t)gr * HID + gc] = f2bf(s);
            }
}

// ---------------- down GEMM + residual + scatter to d_out ----------------
__global__ __launch_bounds__(256, 2) void gemm_down(const unsigned short* __restrict__ act,
                                                    const unsigned short* __restrict__ downT,
                                                    const int* __restrict__ sorted_tok,
                                                    const float* __restrict__ x,
                                                    float* __restrict__ out,
                                                    const int* __restrict__ tile_e,
                                                    const int* __restrict__ tile_row,
                                                    const int* __restrict__ num_tiles) {
    int mt = blockIdx.x;
    if (mt >= *num_tiles) return;
    int n0 = blockIdx.y * BN;
    int e = tile_e[mt], row0 = tile_row[mt];

    __shared__ __align__(16) unsigned short As[BM * BK];
    __shared__ __align__(16) unsigned short Bs[BM * BK];

    const int tid = threadIdx.x;
    const int w = tid >> 6, l = tid & 63;
    const int rl = l & 15, q = l >> 4;
    const int m_off = (w >> 1) * 64, n_off = (w & 1) * 64;
    const int g0 = 2 * w, g1 = 2 * w + 1;

    const unsigned short* gA0 = act + (size_t)(row0 + 16 * g0 + rl) * HID + q * 8;
    const unsigned short* gA1 = act + (size_t)(row0 + 16 * g1 + rl) * HID + q * 8;
    const unsigned short* dnE = downT + (size_t)e * DIM * HID;
    const unsigned short* gB0 = dnE + (size_t)(n0 + 16 * g0 + rl) * HID + q * 8;
    const unsigned short* gB1 = dnE + (size_t)(n0 + 16 * g1 + rl) * HID + q * 8;

    unsigned short* lA0 = As + g0 * 512; unsigned short* lA1 = As + g1 * 512;
    unsigned short* lB0 = Bs + g0 * 512; unsigned short* lB1 = Bs + g1 * 512;

    f32x4 acc[4][4];
#pragma unroll
    for (int i = 0; i < 4; ++i)
#pragma unroll
        for (int j = 0; j < 4; ++j) acc[i][j] = (f32x4){0.f, 0.f, 0.f, 0.f};

    const int mg = (w >> 1) * 4;
    const int ng = (w & 1) * 4;

    const int NT = HID / BK;
    for (int kt = 0; kt < NT; ++kt) {
        if (kt) __syncthreads();
        const int ko = kt * BK;
        async_copy16(gA0 + ko, lA0);
        async_copy16(gA1 + ko, lA1);
        async_copy16(gB0 + ko, lB0);
        async_copy16(gB1 + ko, lB1);
        __syncthreads();

        bf16x8 af[4], bf[4];
#pragma unroll
        for (int mi = 0; mi < 4; ++mi)
            af[mi] = *(const bf16x8*)(As + (mg + mi) * 512 + l * 8);
#pragma unroll
        for (int ni = 0; ni < 4; ++ni)
            bf[ni] = *(const bf16x8*)(Bs + (ng + ni) * 512 + l * 8);
#pragma unroll
        for (int mi = 0; mi < 4; ++mi)
#pragma unroll
            for (int ni = 0; ni < 4; ++ni)
                acc[mi][ni] = __builtin_amdgcn_mfma_f32_16x16x32_bf16(af[mi], bf[ni], acc[mi][ni], 0, 0, 0);
    }

    // epilogue: out[tok] = y + x[tok]; skip padding rows (tok = -1)
#pragma unroll
    for (int mi = 0; mi < 4; ++mi)
#pragma unroll
        for (int r = 0; r < 4; ++r) {
            int gr = row0 + m_off + mi * 16 + q * 4 + r;
            int tok = sorted_tok[gr];
            if (tok >= 0) {
#pragma unroll
                for (int ni = 0; ni < 4; ++ni) {
                    int gc = n0 + n_off + ni * 16 + rl;
                    size_t idx = (size_t)tok * DIM + gc;
                    out[idx] = acc[mi][ni][r] + x[idx];
                }
            }
        }
}

extern "C" void kernel_launch(void* const* d_in, const int* in_sizes, int n_in,
                              void* d_out, int out_size, void* d_ws, size_t ws_size,
                              hipStream_t stream) {
    const float* x      = (const float*)d_in[0];
    const float* scale  = (const float*)d_in[1];
    const float* cent   = (const float*)d_in[2];
    const float* up_w   = (const float*)d_in[3];
    const float* down_w = (const float*)d_in[4];
    float* out = (float*)d_out;
    char* ws = (char*)d_ws;

    // ---- workspace layout (bytes) ----
    int*   counts     = (int*)(ws + 0);      // 8
    int*   cursors    = (int*)(ws + 32);     // 8
    int*   num_tiles  = (int*)(ws + 96);     // 1
    int*   tile_e     = (int*)(ws + 128);    // MTMAX
    int*   tile_row   = (int*)(ws + 416);    // MTMAX
    float* cnorm      = (float*)(ws + 704);  // 8
    int*   ids        = (int*)(ws + 1024);                   // TTOK
    int*   sorted_tok = (int*)(ws + 1024 + TTOK * 4);        // RMAX
    size_t off = 103424;                                     // 256-aligned
    unsigned short* xn    = (unsigned short*)(ws + off);     off += (size_t)TTOK * DIM * 2;
    unsigned short* act   = (unsigned short*)(ws + off);     off += (size_t)RMAX * HID * 2;
    unsigned short* upT   = (unsigned short*)(ws + off);     off += (size_t)NE * 2 * HID * DIM * 2;
    unsigned short* downT = (unsigned short*)(ws + off);     off += (size_t)NE * DIM * HID * 2;

    (void)hipMemsetAsync(ws, 0, 1024, stream);                       // counts/cursors/meta
    (void)hipMemsetAsync(sorted_tok, 0xFF, (size_t)RMAX * 4, stream); // pad rows = -1

    cnorm_k<<<NE, 256, 0, stream>>>(cent, cnorm);
    route_k<<<TTOK, 256, 0, stream>>>(x, scale, cent, cnorm, ids, counts, xn);
    plan_k<<<1, 64, 0, stream>>>(counts, cursors, tile_e, tile_row, num_tiles);
    place_k<<<TTOK / 256, 256, 0, stream>>>(ids, cursors, sorted_tok);

    transpose_w<<<dim3(2 * HID / 64, DIM / 64, NE), dim3(256), 0, stream>>>(up_w, upT, DIM, 2 * HID);
    transpose_w<<<dim3(DIM / 64, HID / 64, NE), dim3(256), 0, stream>>>(down_w, downT, HID, DIM);

    gemm_up<<<dim3(MTMAX, HID / BN), 256, 0, stream>>>(xn, upT, act, sorted_tok,
                                                       tile_e, tile_row, num_tiles);
    gemm_down<<<dim3(MTMAX, DIM / BN), 256, 0, stream>>>(act, downT, sorted_tok, x, out,
                                                         tile_e, tile_row, num_tiles);
}

// Round 4
// 568.809 us; speedup vs baseline: 1.1672x; 1.1238x over previous
//
#include <hip/hip_runtime.h>
#include <hip/hip_bf16.h>
#include <stdint.h>

#define DIM   1024
#define HID   2048
#define NE    8
#define TTOK  8192
#define BM    128
#define BN    128
#define BK    32
#define RMAX  (TTOK + NE * BM)   /* 9216 padded rows max */
#define MTMAX 72                 /* >= 8192/128 + 7 worst-case m-tiles */

typedef __attribute__((ext_vector_type(8))) short bf16x8;
typedef __attribute__((ext_vector_type(8))) unsigned short u16x8;
typedef __attribute__((ext_vector_type(4))) float f32x4;

// fp32 -> bf16 round-to-nearest-even on raw bits
__device__ inline unsigned short f2bf(float f) {
    union { float f; unsigned u; } v; v.f = f;
    unsigned r = v.u + 0x7fffu + ((v.u >> 16) & 1u);
    return (unsigned short)(r >> 16);
}

// async global->LDS, 16B per lane; lds base must be wave-uniform.
// NOTE (R3 lesson): keep the GLOBAL side quad-contiguous — the TA only
// merges consecutive-lane neighborhoods; scattered lane order 4x'd the
// request rate and cost 33% on gemm_up.
__device__ inline void async_copy16(const void* g, void* l) {
    __builtin_amdgcn_global_load_lds(
        (__attribute__((address_space(1))) void*)(void*)g,
        (__attribute__((address_space(3))) void*)l,
        16, 0, 0);
}

// ---------------- centroid norms ----------------
__global__ __launch_bounds__(256) void cnorm_k(const float* __restrict__ cent,
                                               float* __restrict__ cnorm) {
    int e = blockIdx.x, tid = threadIdx.x;
    float4 cv = ((const float4*)(cent + (size_t)e * DIM))[tid];
    float ss = cv.x * cv.x + cv.y * cv.y + cv.z * cv.z + cv.w * cv.w;
#pragma unroll
    for (int off = 32; off; off >>= 1) ss += __shfl_down(ss, off);
    __shared__ float red[4];
    int w = tid >> 6, l = tid & 63;
    if (l == 0) red[w] = ss;
    __syncthreads();
    if (tid == 0) cnorm[e] = red[0] + red[1] + red[2] + red[3];
}

// ------- rmsnorm + routing (fp32 exact) + write bf16 xn in TOKEN order -------
__global__ __launch_bounds__(256) void route_k(const float* __restrict__ x,
                                               const float* __restrict__ scale,
                                               const float* __restrict__ cent,
                                               const float* __restrict__ cnorm,
                                               int* __restrict__ ids,
                                               int* __restrict__ counts,
                                               unsigned short* __restrict__ xn) {
    int t = blockIdx.x, tid = threadIdx.x;
    float4 xv = ((const float4*)(x + (size_t)t * DIM))[tid];
    float4 sv = ((const float4*)scale)[tid];
    float4 xs; xs.x = xv.x * sv.x; xs.y = xv.y * sv.y; xs.z = xv.z * sv.z; xs.w = xv.w * sv.w;
    float ss = xv.x * xv.x + xv.y * xv.y + xv.z * xv.z + xv.w * xv.w;
    float dot[NE];
#pragma unroll
    for (int e = 0; e < NE; ++e) {
        float4 cv = ((const float4*)(cent + (size_t)e * DIM))[tid];
        dot[e] = xs.x * cv.x + xs.y * cv.y + xs.z * cv.z + xs.w * cv.w;
    }
#pragma unroll
    for (int off = 32; off; off >>= 1) {
        ss += __shfl_down(ss, off);
#pragma unroll
        for (int e = 0; e < NE; ++e) dot[e] += __shfl_down(dot[e], off);
    }
    __shared__ float red[4][NE + 1];
    __shared__ float r_sh;
    int w = tid >> 6, l = tid & 63;
    if (l == 0) {
        red[w][0] = ss;
#pragma unroll
        for (int e = 0; e < NE; ++e) red[w][1 + e] = dot[e];
    }
    __syncthreads();
    if (tid == 0) {
        float S = red[0][0] + red[1][0] + red[2][0] + red[3][0];
        float r = rsqrtf(S * (1.0f / DIM) + 1e-6f);
        float best = 3.4e38f; int be = 0;
#pragma unroll
        for (int e = 0; e < NE; ++e) {
            float D = red[0][1 + e] + red[1][1 + e] + red[2][1 + e] + red[3][1 + e];
            float dist = cnorm[e] - 2.0f * r * D;   // nx term dropped (argmin-invariant)
            if (dist < best) { best = dist; be = e; }
        }
        ids[t] = be;
        atomicAdd(&counts[be], 1);
        r_sh = r;
    }
    __syncthreads();
    float r = r_sh;
    ushort4 o;
    o.x = f2bf(xs.x * r); o.y = f2bf(xs.y * r);
    o.z = f2bf(xs.z * r); o.w = f2bf(xs.w * r);
    ((ushort4*)(xn + (size_t)t * DIM))[tid] = o;
}

// ---------------- segment plan + tile map (1 block) ----------------
__global__ void plan_k(const int* __restrict__ counts, int* __restrict__ cursors,
                       int* __restrict__ tile_e, int* __restrict__ tile_row,
                       int* __restrict__ num_tiles) {
    if (threadIdx.x == 0) {
        int row = 0, nt = 0;
        for (int e = 0; e < NE; ++e) {
            cursors[e] = row;
            int c = counts[e];
            int tiles = (c + BM - 1) / BM;
            for (int i = 0; i < tiles; ++i) { tile_e[nt] = e; tile_row[nt] = row + i * BM; ++nt; }
            row += tiles * BM;
        }
        *num_tiles = nt;
    }
}

// ------- assign sorted slots (ballot-aggregated atomics: 1 per wave per expert) -------
__global__ __launch_bounds__(256) void place_k(const int* __restrict__ ids,
                                               int* __restrict__ cursors,
                                               int* __restrict__ sorted_tok) {
    int t = blockIdx.x * 256 + threadIdx.x;
    int e = ids[t];
    int lane = threadIdx.x & 63;
    int pos = 0;
#pragma unroll
    for (int ee = 0; ee < NE; ++ee) {
        unsigned long long grp = __ballot(e == ee);
        if (e == ee) {
            int leader = __ffsll((unsigned long long)grp) - 1;
            int base = 0;
            if (lane == leader) base = atomicAdd(&cursors[ee], (int)__popcll(grp));
            base = __shfl(base, leader);
            pos = base + (int)__popcll(grp & ((1ull << lane) - 1ull));
        }
    }
    sorted_tok[pos] = t;
}

// ------- weight transpose + fp32->bf16: [E][Kd][Nd] -> [E][Nd][Kd] -------
// float4 (16B) global reads, 16B global stores; LDS pitch 70 keeps write
// conflicts at 2-way (free).
__global__ __launch_bounds__(256) void transpose_w(const float* __restrict__ W,
                                                   unsigned short* __restrict__ Wt,
                                                   int Kd, int Nd) {
    __shared__ unsigned short tile[64][70];   // [n][k]
    int e = blockIdx.z;
    const float* src = W + (size_t)e * Kd * Nd;
    unsigned short* dst = Wt + (size_t)e * Kd * Nd;
    int n0 = blockIdx.x * 64, k0 = blockIdx.y * 64;
    int nq = (threadIdx.x & 15) * 4;          // n within tile (float4-wide)
    int kr = threadIdx.x >> 4;                // k row (16 per pass)
#pragma unroll
    for (int p = 0; p < 4; ++p) {
        int i = kr + p * 16;
        float4 v = *(const float4*)(src + (size_t)(k0 + i) * Nd + n0 + nq);
        tile[nq + 0][i] = f2bf(v.x);
        tile[nq + 1][i] = f2bf(v.y);
        tile[nq + 2][i] = f2bf(v.z);
        tile[nq + 3][i] = f2bf(v.w);
    }
    __syncthreads();
    int i = threadIdx.x >> 2;                 // n row
    int j = threadIdx.x & 3;                  // 16-element k chunk
    u16x8 p0, p1;
#pragma unroll
    for (int kk = 0; kk < 8; ++kk) {
        p0[kk] = tile[i][j * 16 + kk];
        p1[kk] = tile[i][j * 16 + 8 + kk];
    }
    unsigned short* drow = dst + (size_t)(n0 + i) * Kd + k0 + j * 16;
    *(u16x8*)drow = p0;                       // 16B-aligned stores
    *(u16x8*)(drow + 8) = p1;
}

// ---------------- up GEMM (dual tile: a & g) + fused swiglu ----------------
// Staging: lane l -> row (l>>2), chunk (l&3)*16B => quad-contiguous 64B global
// reads, row-major LDS (64B rows). Fragment ds_read_b128 has ~2% bank-conflict
// cost (measured R1: 6.7M cycles) — accepted, coalescing matters 15x more.
__global__ __launch_bounds__(256, 2) void gemm_up(const unsigned short* __restrict__ xn,
                                                  const unsigned short* __restrict__ upT,
                                                  unsigned short* __restrict__ act,
                                                  const int* __restrict__ sorted_tok,
                                                  const int* __restrict__ tile_e,
                                                  const int* __restrict__ tile_row,
                                                  const int* __restrict__ num_tiles) {
    int mt = blockIdx.x;
    if (mt >= *num_tiles) return;
    int n0 = blockIdx.y * BN;
    int e = tile_e[mt], row0 = tile_row[mt];

    __shared__ __align__(16) unsigned short As[BM * BK];
    __shared__ __align__(16) unsigned short Ba[BM * BK];
    __shared__ __align__(16) unsigned short Bg[BM * BK];

    const int tid = threadIdx.x;
    const int w = tid >> 6, l = tid & 63;
    const int rl = l & 15, q = l >> 4;
    const int m_off = (w >> 1) * 64, n_off = (w & 1) * 64;
    const int g0 = 2 * w, g1 = 2 * w + 1;

    const int sr = l >> 2;            // row within 16-row staging group
    const int sc = (l & 3) * 8;       // k-chunk (elements, 16B)

    // A rows indirect through sorted_tok (quad-contiguous 64B per token row);
    // pad rows (-1) clamp to 0 (dead data)
    int tok0 = sorted_tok[row0 + 16 * g0 + sr]; if (tok0 < 0) tok0 = 0;
    int tok1 = sorted_tok[row0 + 16 * g1 + sr]; if (tok1 < 0) tok1 = 0;
    const unsigned short* gA0 = xn + (size_t)tok0 * DIM + sc;
    const unsigned short* gA1 = xn + (size_t)tok1 * DIM + sc;
    const unsigned short* upE = upT + (size_t)e * (2 * HID) * DIM;
    const unsigned short* gBa0 = upE + (size_t)(n0 + 16 * g0 + sr) * DIM + sc;
    const unsigned short* gBa1 = upE + (size_t)(n0 + 16 * g1 + sr) * DIM + sc;
    const unsigned short* gBg0 = upE + (size_t)(HID + n0 + 16 * g0 + sr) * DIM + sc;
    const unsigned short* gBg1 = upE + (size_t)(HID + n0 + 16 * g1 + sr) * DIM + sc;

    unsigned short* lA0 = As + g0 * 512;  unsigned short* lA1 = As + g1 * 512;
    unsigned short* lBa0 = Ba + g0 * 512; unsigned short* lBa1 = Ba + g1 * 512;
    unsigned short* lBg0 = Bg + g0 * 512; unsigned short* lBg1 = Bg + g1 * 512;

    f32x4 accA[4][4], accG[4][4];
#pragma unroll
    for (int i = 0; i < 4; ++i)
#pragma unroll
        for (int j = 0; j < 4; ++j) {
            accA[i][j] = (f32x4){0.f, 0.f, 0.f, 0.f};
            accG[i][j] = (f32x4){0.f, 0.f, 0.f, 0.f};
        }

    const int NT = DIM / BK;
    for (int kt = 0; kt < NT; ++kt) {
        if (kt) __syncthreads();
        const int ko = kt * BK;
        async_copy16(gA0 + ko, lA0);
        async_copy16(gA1 + ko, lA1);
        async_copy16(gBa0 + ko, lBa0);
        async_copy16(gBa1 + ko, lBa1);
        async_copy16(gBg0 + ko, lBg0);
        async_copy16(gBg1 + ko, lBg1);
        __syncthreads();

        bf16x8 af[4], ba[4], bg[4];
#pragma unroll
        for (int mi = 0; mi < 4; ++mi)
            af[mi] = *(const bf16x8*)(As + (m_off + mi * 16 + rl) * BK + q * 8);
#pragma unroll
        for (int ni = 0; ni < 4; ++ni) {
            ba[ni] = *(const bf16x8*)(Ba + (n_off + ni * 16 + rl) * BK + q * 8);
            bg[ni] = *(const bf16x8*)(Bg + (n_off + ni * 16 + rl) * BK + q * 8);
        }
#pragma unroll
        for (int mi = 0; mi < 4; ++mi)
#pragma unroll
            for (int ni = 0; ni < 4; ++ni) {
                accA[mi][ni] = __builtin_amdgcn_mfma_f32_16x16x32_bf16(af[mi], ba[ni], accA[mi][ni], 0, 0, 0);
                accG[mi][ni] = __builtin_amdgcn_mfma_f32_16x16x32_bf16(af[mi], bg[ni], accG[mi][ni], 0, 0, 0);
            }
    }

    // epilogue: act = a * silu(g), bf16 (pad rows write garbage -> dead)
#pragma unroll
    for (int mi = 0; mi < 4; ++mi)
#pragma unroll
        for (int ni = 0; ni < 4; ++ni)
#pragma unroll
            for (int r = 0; r < 4; ++r) {
                float a = accA[mi][ni][r];
                float g = accG[mi][ni][r];
                float s = a * (g / (1.0f + __expf(-g)));
                int gr = row0 + m_off + mi * 16 + q * 4 + r;
                int gc = n0 + n_off + ni * 16 + rl;
                act[(size_t)gr * HID + gc] = f2bf(s);
            }
}

// ---------------- down GEMM + residual + scatter to d_out ----------------
__global__ __launch_bounds__(256, 2) void gemm_down(const unsigned short* __restrict__ act,
                                                    const unsigned short* __restrict__ downT,
                                                    const int* __restrict__ sorted_tok,
                                                    const float* __restrict__ x,
                                                    float* __restrict__ out,
                                                    const int* __restrict__ tile_e,
                                                    const int* __restrict__ tile_row,
                                                    const int* __restrict__ num_tiles) {
    int mt = blockIdx.x;
    if (mt >= *num_tiles) return;
    int n0 = blockIdx.y * BN;
    int e = tile_e[mt], row0 = tile_row[mt];

    __shared__ __align__(16) unsigned short As[BM * BK];
    __shared__ __align__(16) unsigned short Bs[BM * BK];

    const int tid = threadIdx.x;
    const int w = tid >> 6, l = tid & 63;
    const int rl = l & 15, q = l >> 4;
    const int m_off = (w >> 1) * 64, n_off = (w & 1) * 64;
    const int g0 = 2 * w, g1 = 2 * w + 1;

    const int sr = l >> 2;
    const int sc = (l & 3) * 8;

    const unsigned short* gA0 = act + (size_t)(row0 + 16 * g0 + sr) * HID + sc;
    const unsigned short* gA1 = act + (size_t)(row0 + 16 * g1 + sr) * HID + sc;
    const unsigned short* dnE = downT + (size_t)e * DIM * HID;
    const unsigned short* gB0 = dnE + (size_t)(n0 + 16 * g0 + sr) * HID + sc;
    const unsigned short* gB1 = dnE + (size_t)(n0 + 16 * g1 + sr) * HID + sc;

    unsigned short* lA0 = As + g0 * 512; unsigned short* lA1 = As + g1 * 512;
    unsigned short* lB0 = Bs + g0 * 512; unsigned short* lB1 = Bs + g1 * 512;

    f32x4 acc[4][4];
#pragma unroll
    for (int i = 0; i < 4; ++i)
#pragma unroll
        for (int j = 0; j < 4; ++j) acc[i][j] = (f32x4){0.f, 0.f, 0.f, 0.f};

    const int NT = HID / BK;
    for (int kt = 0; kt < NT; ++kt) {
        if (kt) __syncthreads();
        const int ko = kt * BK;
        async_copy16(gA0 + ko, lA0);
        async_copy16(gA1 + ko, lA1);
        async_copy16(gB0 + ko, lB0);
        async_copy16(gB1 + ko, lB1);
        __syncthreads();

        bf16x8 af[4], bf[4];
#pragma unroll
        for (int mi = 0; mi < 4; ++mi)
            af[mi] = *(const bf16x8*)(As + (m_off + mi * 16 + rl) * BK + q * 8);
#pragma unroll
        for (int ni = 0; ni < 4; ++ni)
            bf[ni] = *(const bf16x8*)(Bs + (n_off + ni * 16 + rl) * BK + q * 8);
#pragma unroll
        for (int mi = 0; mi < 4; ++mi)
#pragma unroll
            for (int ni = 0; ni < 4; ++ni)
                acc[mi][ni] = __builtin_amdgcn_mfma_f32_16x16x32_bf16(af[mi], bf[ni], acc[mi][ni], 0, 0, 0);
    }

    // epilogue: out[tok] = y + x[tok]; skip padding rows (tok = -1)
#pragma unroll
    for (int mi = 0; mi < 4; ++mi)
#pragma unroll
        for (int r = 0; r < 4; ++r) {
            int gr = row0 + m_off + mi * 16 + q * 4 + r;
            int tok = sorted_tok[gr];
            if (tok >= 0) {
#pragma unroll
                for (int ni = 0; ni < 4; ++ni) {
                    int gc = n0 + n_off + ni * 16 + rl;
                    size_t idx = (size_t)tok * DIM + gc;
                    out[idx] = acc[mi][ni][r] + x[idx];
                }
            }
        }
}

extern "C" void kernel_launch(void* const* d_in, const int* in_sizes, int n_in,
                              void* d_out, int out_size, void* d_ws, size_t ws_size,
                              hipStream_t stream) {
    const float* x      = (const float*)d_in[0];
    const float* scale  = (const float*)d_in[1];
    const float* cent   = (const float*)d_in[2];
    const float* up_w   = (const float*)d_in[3];
    const float* down_w = (const float*)d_in[4];
    float* out = (float*)d_out;
    char* ws = (char*)d_ws;

    // ---- workspace layout (bytes) ----
    int*   counts     = (int*)(ws + 0);      // 8
    int*   cursors    = (int*)(ws + 32);     // 8
    int*   num_tiles  = (int*)(ws + 96);     // 1
    int*   tile_e     = (int*)(ws + 128);    // MTMAX
    int*   tile_row   = (int*)(ws + 416);    // MTMAX
    float* cnorm      = (float*)(ws + 704);  // 8
    int*   ids        = (int*)(ws + 1024);                   // TTOK
    int*   sorted_tok = (int*)(ws + 1024 + TTOK * 4);        // RMAX
    size_t off = 103424;                                     // 256-aligned
    unsigned short* xn    = (unsigned short*)(ws + off);     off += (size_t)TTOK * DIM * 2;
    unsigned short* act   = (unsigned short*)(ws + off);     off += (size_t)RMAX * HID * 2;
    unsigned short* upT   = (unsigned short*)(ws + off);     off += (size_t)NE * 2 * HID * DIM * 2;
    unsigned short* downT = (unsigned short*)(ws + off);     off += (size_t)NE * DIM * HID * 2;

    (void)hipMemsetAsync(ws, 0, 1024, stream);                        // counts/cursors/meta
    (void)hipMemsetAsync(sorted_tok, 0xFF, (size_t)RMAX * 4, stream); // pad rows = -1

    cnorm_k<<<NE, 256, 0, stream>>>(cent, cnorm);
    route_k<<<TTOK, 256, 0, stream>>>(x, scale, cent, cnorm, ids, counts, xn);
    plan_k<<<1, 64, 0, stream>>>(counts, cursors, tile_e, tile_row, num_tiles);
    place_k<<<TTOK / 256, 256, 0, stream>>>(ids, cursors, sorted_tok);

    transpose_w<<<dim3(2 * HID / 64, DIM / 64, NE), dim3(256), 0, stream>>>(up_w, upT, DIM, 2 * HID);
    transpose_w<<<dim3(DIM / 64, HID / 64, NE), dim3(256), 0, stream>>>(down_w, downT, HID, DIM);

    gemm_up<<<dim3(MTMAX, HID / BN), 256, 0, stream>>>(xn, upT, act, sorted_tok,
                                                       tile_e, tile_row, num_tiles);
    gemm_down<<<dim3(MTMAX, DIM / BN), 256, 0, stream>>>(act, downT, sorted_tok, x, out,
                                                         tile_e, tile_row, num_tiles);
}